// Round 1
// 1219.608 us; speedup vs baseline: 1.3566x; 1.3566x over previous
//
#include <hip/hip_runtime.h>
#include <hip/hip_bf16.h>

#define N_NODES 100000
#define N_EDGES 3200000
#define E_GROUPS (N_EDGES / 8)   // 8 edges per wave-iteration
#define N_GROUPS (N_NODES / 8)   // 8 nodes per wave-iteration
#define NXCD 8
#define NUP_STRIDE (N_NODES * 32)   // floats per XCD-private accumulator copy

// weight sub-offsets in g_W
#define EW1_O 0        // 88*32
#define EB1_O 2816     // 32
#define EW2_O 2848     // 32*32
#define EB2_O 3872     // 32
#define NW1_O 3904     // 71*32
#define NB1_O 6176     // 32
#define NW2_O 6208     // 32
#define NB2_O 6240     // 1

// Device-global state: independent of ws_size. Rebuilt from inputs on EVERY call.
// g_nup: 8 XCD-private copies (102.4 MB). Atomics are XCD-local (L2-scope, no sc1);
// node_kernel sums the 8 copies. Correct because each copy is only ever touched by
// waves resident on that XCD (HW_REG_XCC_ID), and dispatch-end L2 writeback makes
// the values visible to the next kernel.
__device__ float g_nup[NXCD * NUP_STRIDE];
__device__ float g_W[6244];             // converted weights
__device__ int   g_flags[2];            // [0]: 1=bf16 floats; [1]: 1=int64 idx

__device__ __forceinline__ float bf2f(unsigned short u) {
    union { unsigned int i; float f; } c;
    c.i = ((unsigned int)u) << 16;
    return c.f;
}

__device__ __forceinline__ float rd_any(const void* p, int i, bool bf) {
    if (bf) return bf2f(((const unsigned short*)p)[i]);
    return ((const float*)p)[i];
}

// tanh via hardware exp2: ~6 VALU inst. |err| ~1e-6 (validated: absmax 9.8e-4 in r6).
__device__ __forceinline__ float fast_tanh(float x) {
    float ax = fabsf(x);
    float e  = __expf(ax * 2.0f);
    float t  = 1.0f - 2.0f / (e + 1.0f);
    return copysignf(t, x);
}

__global__ void detect_kernel(const unsigned short* __restrict__ ew1_raw,
                              const int* __restrict__ ei32) {
    __shared__ int s_ok, s_nzodd;
    if (threadIdx.x == 0) { s_ok = 1; s_nzodd = 0; }
    __syncthreads();
    bool ok = true;
    for (int i = threadIdx.x; i < 2816; i += 256) {
        float v = bf2f(ew1_raw[i]);
        if (!(fabsf(v) <= 0.25f)) ok = false;
    }
    if (!ok) atomicAnd(&s_ok, 0);
    int cnt = 0;
    for (int i = threadIdx.x; i < 2048; i += 256)
        if (ei32[2 * i + 1] != 0) cnt++;
    if (cnt) atomicAdd(&s_nzodd, cnt);
    __syncthreads();
    if (threadIdx.x == 0) {
        g_flags[0] = s_ok;
        g_flags[1] = (s_nzodd < 16) ? 1 : 0;
    }
}

__global__ void zero_nup_kernel() {
    int i = blockIdx.x * 256 + threadIdx.x;
    if (i < NXCD * NUP_STRIDE / 4) ((float4*)g_nup)[i] = make_float4(0.f, 0.f, 0.f, 0.f);
}

__global__ void cvt_weights_kernel(const void* ew1, const void* eb1,
                                   const void* ew2, const void* eb2,
                                   const void* nw1, const void* nb1,
                                   const void* nw2, const void* nb2) {
    bool bf = (g_flags[0] != 0);
    int t = blockIdx.x * blockDim.x + threadIdx.x;
    int S = gridDim.x * blockDim.x;
    for (int i = t; i < 2816; i += S) g_W[EW1_O + i] = rd_any(ew1, i, bf);
    for (int i = t; i < 32;   i += S) g_W[EB1_O + i] = rd_any(eb1, i, bf);
    for (int i = t; i < 1024; i += S) g_W[EW2_O + i] = rd_any(ew2, i, bf);
    for (int i = t; i < 32;   i += S) g_W[EB2_O + i] = rd_any(eb2, i, bf);
    for (int i = t; i < 2272; i += S) g_W[NW1_O + i] = rd_any(nw1, i, bf);
    for (int i = t; i < 32;   i += S) g_W[NB1_O + i] = rd_any(nb1, i, bf);
    for (int i = t; i < 32;   i += S) g_W[NW2_O + i] = rd_any(nw2, i, bf);
    if (t == 0) g_W[NB2_O] = rd_any(nb2, 0, bf);
}

// Wave-cooperative edge MLP, ILP-4, 1-deep software pipeline:
//   iter g: [issue idx(g+1)] [commit regs(g)->LDS] [layer1] [issue gather(g+1)->regs]
//           [layer2] [L2-local atomics(g)]
// Atomics are issued AFTER the next group's gathers, so the vmcnt wait at the LDS
// commit leaves them in flight (never drains atomic commit on the critical path).
// w2 moved from pinned VGPRs to LDS (broadcast reads) to cut register pressure.
__launch_bounds__(256, 2)
__global__ void edge_kernel(const void* __restrict__ nraw,   // [N,39]
                            const void* __restrict__ eraw,   // [E,10]
                            const int*  __restrict__ ei) {   // [2,E]
    const int lane = threadIdx.x & 63;
    const int wv   = threadIdx.x >> 6;
    const int jcol = lane & 31;
    const int half = lane >> 5;
    const bool bf  = (g_flags[0] != 0);
    const bool i64 = (g_flags[1] != 0);

    float w1c[88];
#pragma unroll
    for (int r = 0; r < 88; r++) w1c[r] = g_W[EW1_O + r * 32 + jcol];
    // pin: forbid rematerialization/spill of the weight columns (r6: VGPR=84 proved remat)
#pragma unroll
    for (int r = 0; r < 88; r++) asm volatile("" : "+v"(w1c[r]));
    const float b1 = g_W[EB1_O + jcol];
    const float b2 = g_W[EB2_O + jcol];

    __shared__ __align__(16) float sx[4][4][2][96];  // [wave][s][half][x-row]
    __shared__ __align__(16) float sh[4][4][2][32];  // h rows
    __shared__ __align__(16) float s_w2[1024];       // w2 columns (broadcast reads)
    for (int i = threadIdx.x; i < 1024; i += 256) s_w2[i] = g_W[EW2_O + i];
    __syncthreads();

    // XCD-private accumulator slice: atomics stay in this XCD's L2
    unsigned xcc;
    asm volatile("s_getreg_b32 %0, hwreg(HW_REG_XCC_ID)" : "=s"(xcc));
    float* nup = g_nup + (xcc & 7) * NUP_STRIDE;

    const unsigned short* n16 = (const unsigned short*)nraw;
    const unsigned short* e16 = (const unsigned short*)eraw;
    const float*          n32 = (const float*)nraw;
    const float*          e32 = (const float*)eraw;

    const int stride = gridDim.x * 4;
    int g = blockIdx.x * 4 + wv;
    if (g >= E_GROUPS) return;   // never taken at grid=1024 (after the one barrier)

    int   rs[4], rd[4];    // raw (unclamped, low-dword) index prefetch
    float xr[12];          // gathered x prefetch (3 per edge-slot)
    int   srcs[4], srcs_n[4];

    auto issue_idx = [&](int gg) {
        const int e0 = gg * 8 + half * 4;
#pragma unroll
        for (int s = 0; s < 4; s++) {
            const int eh = e0 + s;
            // i64: load low dword only (values < 2^31) -> no truncation op, wait deferred
            if (i64) { rs[s] = ei[2 * eh]; rd[s] = ei[2 * (N_EDGES + eh)]; }
            else     { rs[s] = ei[eh];     rd[s] = ei[N_EDGES + eh]; }
        }
    };

    auto issue_gather = [&](int gg, int* sv_out) {
        const int e0 = gg * 8 + half * 4;
#pragma unroll
        for (int s = 0; s < 4; s++) {
            int sv = rs[s]; if ((unsigned)sv >= N_NODES) sv = 0;
            int dv = rd[s]; if ((unsigned)dv >= N_NODES) dv = 0;
            sv_out[s] = sv;
            const int eh = e0 + s;
#pragma unroll
            for (int it = 0; it < 3; it++) {
                const int t = jcol + it * 32;
                float v = 0.0f;
                if (t < 88) {
                    if (t < 39)      v = bf ? bf2f(n16[sv * 39 + t])
                                            : n32[sv * 39 + t];
                    else if (t < 49) v = bf ? bf2f(e16[(long long)eh * 10 + (t - 39)])
                                            : e32[(long long)eh * 10 + (t - 39)];
                    else             v = bf ? bf2f(n16[dv * 39 + (t - 49)])
                                            : n32[dv * 39 + (t - 49)];
                }
                xr[s * 3 + it] = v;
            }
        }
    };

    // prologue: fill the pipe for the first group
    issue_idx(g);
    issue_gather(g, srcs);

    while (true) {
        const int  gn = g + stride;
        const bool hn = (gn < E_GROUPS);
        if (hn) issue_idx(gn);

        // commit prefetched x -> LDS (waits on the 12 gathers only; idx loads and
        // the previous group's atomics are newer in the vmcnt queue -> stay in flight)
#pragma unroll
        for (int s = 0; s < 4; s++)
#pragma unroll
            for (int it = 0; it < 3; it++) {
                const int t = jcol + it * 32;
                if (t < 88) sx[wv][s][half][t] = xr[s * 3 + it];
            }

        // layer 1: 4 independent accumulator chains (ILP-4 hides 4-cyc fmac latency)
        float acc0 = b1, acc1 = b1, acc2 = b1, acc3 = b1;
#pragma unroll
        for (int q = 0; q < 22; q++) {
            float4 x0 = ((const float4*)sx[wv][0][half])[q];
            float4 x1 = ((const float4*)sx[wv][1][half])[q];
            float4 x2 = ((const float4*)sx[wv][2][half])[q];
            float4 x3 = ((const float4*)sx[wv][3][half])[q];
            acc0 = fmaf(x0.x, w1c[4*q+0], acc0); acc0 = fmaf(x0.y, w1c[4*q+1], acc0);
            acc0 = fmaf(x0.z, w1c[4*q+2], acc0); acc0 = fmaf(x0.w, w1c[4*q+3], acc0);
            acc1 = fmaf(x1.x, w1c[4*q+0], acc1); acc1 = fmaf(x1.y, w1c[4*q+1], acc1);
            acc1 = fmaf(x1.z, w1c[4*q+2], acc1); acc1 = fmaf(x1.w, w1c[4*q+3], acc1);
            acc2 = fmaf(x2.x, w1c[4*q+0], acc2); acc2 = fmaf(x2.y, w1c[4*q+1], acc2);
            acc2 = fmaf(x2.z, w1c[4*q+2], acc2); acc2 = fmaf(x2.w, w1c[4*q+3], acc2);
            acc3 = fmaf(x3.x, w1c[4*q+0], acc3); acc3 = fmaf(x3.y, w1c[4*q+1], acc3);
            acc3 = fmaf(x3.z, w1c[4*q+2], acc3); acc3 = fmaf(x3.w, w1c[4*q+3], acc3);
        }
        sh[wv][0][half][jcol] = fast_tanh(acc0);
        sh[wv][1][half][jcol] = fast_tanh(acc1);
        sh[wv][2][half][jcol] = fast_tanh(acc2);
        sh[wv][3][half][jcol] = fast_tanh(acc3);

        // prefetch next group's gathers into regs (HBM/L2 latency hides under layer 2)
        if (hn) issue_gather(gn, srcs_n);

        // layer 2, same ILP-4; w2 from LDS (2-way broadcast, conflict-free)
        float a0 = b2, a1 = b2, a2 = b2, a3 = b2;
#pragma unroll
        for (int q = 0; q < 8; q++) {
            float4 h0 = ((const float4*)sh[wv][0][half])[q];
            float4 h1 = ((const float4*)sh[wv][1][half])[q];
            float4 h2 = ((const float4*)sh[wv][2][half])[q];
            float4 h3 = ((const float4*)sh[wv][3][half])[q];
            const float wa = s_w2[(4*q+0)*32 + jcol];
            const float wb = s_w2[(4*q+1)*32 + jcol];
            const float wc = s_w2[(4*q+2)*32 + jcol];
            const float wd = s_w2[(4*q+3)*32 + jcol];
            a0 = fmaf(h0.x, wa, a0); a0 = fmaf(h0.y, wb, a0);
            a0 = fmaf(h0.z, wc, a0); a0 = fmaf(h0.w, wd, a0);
            a1 = fmaf(h1.x, wa, a1); a1 = fmaf(h1.y, wb, a1);
            a1 = fmaf(h1.z, wc, a1); a1 = fmaf(h1.w, wd, a1);
            a2 = fmaf(h2.x, wa, a2); a2 = fmaf(h2.y, wb, a2);
            a2 = fmaf(h2.z, wc, a2); a2 = fmaf(h2.w, wd, a2);
            a3 = fmaf(h3.x, wa, a3); a3 = fmaf(h3.y, wb, a3);
            a3 = fmaf(h3.z, wc, a3); a3 = fmaf(h3.w, wd, a3);
        }

        // coalesced wave-atomics into the XCD-private slice: L2-scope (no sc1),
        // no return value -> fire-and-forget, commits under the next iteration
        __hip_atomic_fetch_add(&nup[srcs[0] * 32 + jcol], fast_tanh(a0),
                               __ATOMIC_RELAXED, __HIP_MEMORY_SCOPE_WORKGROUP);
        __hip_atomic_fetch_add(&nup[srcs[1] * 32 + jcol], fast_tanh(a1),
                               __ATOMIC_RELAXED, __HIP_MEMORY_SCOPE_WORKGROUP);
        __hip_atomic_fetch_add(&nup[srcs[2] * 32 + jcol], fast_tanh(a2),
                               __ATOMIC_RELAXED, __HIP_MEMORY_SCOPE_WORKGROUP);
        __hip_atomic_fetch_add(&nup[srcs[3] * 32 + jcol], fast_tanh(a3),
                               __ATOMIC_RELAXED, __HIP_MEMORY_SCOPE_WORKGROUP);

        if (!hn) break;
        g = gn;
#pragma unroll
        for (int s = 0; s < 4; s++) srcs[s] = srcs_n[s];
    }
}

// Wave-cooperative node MLP, ILP-4: one wave = 8 nodes. Sums the 8 XCD-private
// n_up copies during the gather phase (streams 102 MB, ~16 us at HBM BW).
__launch_bounds__(256, 2)
__global__ void node_kernel(const void* __restrict__ nraw,
                            float* __restrict__ out) {
    const int lane = threadIdx.x & 63;
    const int wv   = threadIdx.x >> 6;
    const int jcol = lane & 31;
    const int half = lane >> 5;
    const bool bf  = (g_flags[0] != 0);

    float w1c[72];
#pragma unroll
    for (int r = 0; r < 71; r++) w1c[r] = g_W[NW1_O + r * 32 + jcol];
    w1c[71] = 0.0f;
#pragma unroll
    for (int r = 0; r < 72; r++) asm volatile("" : "+v"(w1c[r]));
    const float w2e = g_W[NW2_O + jcol];
    const float b1  = g_W[NB1_O + jcol];
    const float b2  = g_W[NB2_O];

    __shared__ __align__(16) float sx[4][4][2][72];  // [nup(32)|n(39)|pad]

    const unsigned short* n16 = (const unsigned short*)nraw;
    const float*          n32 = (const float*)nraw;

    int gw = blockIdx.x * 4 + wv;
    int stride = gridDim.x * 4;
    for (int g = gw; g < N_GROUPS; g += stride) {
        const int id0 = g * 8 + half * 4;
#pragma unroll
        for (int s = 0; s < 4; s++) {
            const int id = id0 + s;
#pragma unroll
            for (int it = 0; it < 3; it++) {
                int t = jcol + it * 32;
                if (t < 72) {
                    float v;
                    if (t < 32) {
                        const float* p = g_nup + id * 32 + t;
                        v = p[0];
#pragma unroll
                        for (int x = 1; x < NXCD; x++) v += p[x * NUP_STRIDE];
                    }
                    else if (t < 71) v = bf ? bf2f(n16[id * 39 + (t - 32)])
                                            : n32[id * 39 + (t - 32)];
                    else             v = 0.0f;
                    sx[wv][s][half][t] = v;
                }
            }
        }
        float acc0 = b1, acc1 = b1, acc2 = b1, acc3 = b1;
#pragma unroll
        for (int q = 0; q < 18; q++) {
            float4 x0 = ((const float4*)sx[wv][0][half])[q];
            float4 x1 = ((const float4*)sx[wv][1][half])[q];
            float4 x2 = ((const float4*)sx[wv][2][half])[q];
            float4 x3 = ((const float4*)sx[wv][3][half])[q];
            acc0 = fmaf(x0.x, w1c[4*q+0], acc0); acc0 = fmaf(x0.y, w1c[4*q+1], acc0);
            acc0 = fmaf(x0.z, w1c[4*q+2], acc0); acc0 = fmaf(x0.w, w1c[4*q+3], acc0);
            acc1 = fmaf(x1.x, w1c[4*q+0], acc1); acc1 = fmaf(x1.y, w1c[4*q+1], acc1);
            acc1 = fmaf(x1.z, w1c[4*q+2], acc1); acc1 = fmaf(x1.w, w1c[4*q+3], acc1);
            acc2 = fmaf(x2.x, w1c[4*q+0], acc2); acc2 = fmaf(x2.y, w1c[4*q+1], acc2);
            acc2 = fmaf(x2.z, w1c[4*q+2], acc2); acc2 = fmaf(x2.w, w1c[4*q+3], acc2);
            acc3 = fmaf(x3.x, w1c[4*q+0], acc3); acc3 = fmaf(x3.y, w1c[4*q+1], acc3);
            acc3 = fmaf(x3.z, w1c[4*q+2], acc3); acc3 = fmaf(x3.w, w1c[4*q+3], acc3);
        }
        float t0 = fast_tanh(acc0) * w2e;
        float t1 = fast_tanh(acc1) * w2e;
        float t2 = fast_tanh(acc2) * w2e;
        float t3 = fast_tanh(acc3) * w2e;
#pragma unroll
        for (int m = 1; m < 32; m <<= 1) {
            t0 += __shfl_xor(t0, m, 64);
            t1 += __shfl_xor(t1, m, 64);
            t2 += __shfl_xor(t2, m, 64);
            t3 += __shfl_xor(t3, m, 64);
        }
        if (jcol == 0) {
            out[id0 + 0] = t0 + b2;
            out[id0 + 1] = t1 + b2;
            out[id0 + 2] = t2 + b2;
            out[id0 + 3] = t3 + b2;
        }
    }
}

extern "C" void kernel_launch(void* const* d_in, const int* in_sizes, int n_in,
                              void* d_out, int out_size, void* d_ws, size_t ws_size,
                              hipStream_t stream) {
    const void* n_raw = d_in[0];
    const void* e_raw = d_in[1];
    const int*  ei    = (const int*)d_in[2];
    // d_in[3] = batch (unused)

    detect_kernel<<<1, 256, 0, stream>>>((const unsigned short*)d_in[4], ei);
    zero_nup_kernel<<<(NXCD * NUP_STRIDE / 4 + 255) / 256, 256, 0, stream>>>();
    cvt_weights_kernel<<<16, 256, 0, stream>>>(d_in[4], d_in[5], d_in[6], d_in[7],
                                               d_in[8], d_in[9], d_in[10], d_in[11]);
    edge_kernel<<<1024, 256, 0, stream>>>(n_raw, e_raw, ei);
    node_kernel<<<512, 256, 0, stream>>>(n_raw, (float*)d_out);
}

// Round 2
// 1057.244 us; speedup vs baseline: 1.5650x; 1.1536x over previous
//
#include <hip/hip_runtime.h>
#include <hip/hip_bf16.h>

#define N_NODES 100000
#define N_EDGES 3200000
#define E_GROUPS (N_EDGES / 8)   // VALU fallback: 8 edges per wave-iteration
#define E_TILES  (N_EDGES / 16)  // MFMA path: 16 edges per wave-iteration
#define N_GROUPS (N_NODES / 8)   // 8 nodes per wave-iteration
#define NXCD 8
#define NUP_STRIDE (N_NODES * 32)   // floats per XCD-private accumulator copy

// weight sub-offsets in g_W (fp32 copies)
#define EW1_O 0        // 88*32
#define EB1_O 2816     // 32
#define EW2_O 2848     // 32*32
#define EB2_O 3872     // 32
#define NW1_O 3904     // 71*32
#define NB1_O 6176     // 32
#define NW2_O 6208     // 32
#define NB2_O 6240     // 1

typedef unsigned short ushort_t;
typedef __attribute__((ext_vector_type(8))) short bf16x8;
typedef __attribute__((ext_vector_type(4))) float f32x4;

// Device-global state, rebuilt from inputs on EVERY call.
__device__ float    g_nup[NXCD * NUP_STRIDE];  // 8 XCD-private scatter copies
__device__ float    g_W[6244];                 // fp32 weights
__device__ ushort_t g_Wbf1[96 * 32];           // W1 bf16, K padded 88->96 (pad rows zero)
__device__ ushort_t g_Wbf2[32 * 32];           // W2 bf16
__device__ int      g_flags[2];                // [0]: 1=bf16 floats; [1]: 1=int64 idx

__device__ __forceinline__ float bf2f(unsigned short u) {
    union { unsigned int i; float f; } c;
    c.i = ((unsigned int)u) << 16;
    return c.f;
}

__device__ __forceinline__ unsigned short f2bf_rne(float f) {
    union { float f; unsigned int u; } c;
    c.f = f;
    unsigned int u = c.u + 0x7FFFu + ((c.u >> 16) & 1u);
    return (unsigned short)(u >> 16);
}

__device__ __forceinline__ float rd_any(const void* p, int i, bool bf) {
    if (bf) return bf2f(((const unsigned short*)p)[i]);
    return ((const float*)p)[i];
}

// tanh via hardware exp2: ~6 VALU inst. |err| ~1e-6 (validated: absmax 9.8e-4).
__device__ __forceinline__ float fast_tanh(float x) {
    float ax = fabsf(x);
    float e  = __expf(ax * 2.0f);
    float t  = 1.0f - 2.0f / (e + 1.0f);
    return copysignf(t, x);
}

__global__ void detect_kernel(const unsigned short* __restrict__ ew1_raw,
                              const int* __restrict__ ei32) {
    __shared__ int s_ok, s_nzodd;
    if (threadIdx.x == 0) { s_ok = 1; s_nzodd = 0; }
    __syncthreads();
    bool ok = true;
    for (int i = threadIdx.x; i < 2816; i += 256) {
        float v = bf2f(ew1_raw[i]);
        if (!(fabsf(v) <= 0.25f)) ok = false;
    }
    if (!ok) atomicAnd(&s_ok, 0);
    int cnt = 0;
    for (int i = threadIdx.x; i < 2048; i += 256)
        if (ei32[2 * i + 1] != 0) cnt++;
    if (cnt) atomicAdd(&s_nzodd, cnt);
    __syncthreads();
    if (threadIdx.x == 0) {
        g_flags[0] = s_ok;
        g_flags[1] = (s_nzodd < 16) ? 1 : 0;
    }
}

__global__ void zero_nup_kernel() {
    int i = blockIdx.x * 256 + threadIdx.x;
    if (i < NXCD * NUP_STRIDE / 4) ((float4*)g_nup)[i] = make_float4(0.f, 0.f, 0.f, 0.f);
}

__global__ void cvt_weights_kernel(const void* ew1, const void* eb1,
                                   const void* ew2, const void* eb2,
                                   const void* nw1, const void* nb1,
                                   const void* nw2, const void* nb2) {
    bool bf = (g_flags[0] != 0);
    int t = blockIdx.x * blockDim.x + threadIdx.x;
    int S = gridDim.x * blockDim.x;
    for (int i = t; i < 2816; i += S) g_W[EW1_O + i] = rd_any(ew1, i, bf);
    for (int i = t; i < 32;   i += S) g_W[EB1_O + i] = rd_any(eb1, i, bf);
    for (int i = t; i < 1024; i += S) g_W[EW2_O + i] = rd_any(ew2, i, bf);
    for (int i = t; i < 32;   i += S) g_W[EB2_O + i] = rd_any(eb2, i, bf);
    for (int i = t; i < 2272; i += S) g_W[NW1_O + i] = rd_any(nw1, i, bf);
    for (int i = t; i < 32;   i += S) g_W[NB1_O + i] = rd_any(nb1, i, bf);
    for (int i = t; i < 32;   i += S) g_W[NW2_O + i] = rd_any(nw2, i, bf);
    if (t == 0) g_W[NB2_O] = rd_any(nb2, 0, bf);
    // bf16 copies for the MFMA path (K padded to 96 with zero rows so LDS pad
    // garbage in X can never produce NaN: X_pad is zeroed too, W pad rows are 0)
    for (int i = t; i < 96 * 32; i += S) {
        int r = i >> 5;
        ushort_t v = 0;
        if (r < 88) v = bf ? ((const ushort_t*)ew1)[i] : f2bf_rne(((const float*)ew1)[i]);
        g_Wbf1[i] = v;
    }
    for (int i = t; i < 1024; i += S)
        g_Wbf2[i] = bf ? ((const ushort_t*)ew2)[i] : f2bf_rne(((const float*)ew2)[i]);
}

// ---------------------------------------------------------------------------
// MFMA edge path (bf16 inputs only). One wave = 16 edges per iteration.
//   layer1: X[16x96]bf16 @ W1[96x32]bf16 -> 6 mfma_f32_16x16x32_bf16
//   layer2: split-bf16 h (h_hi + h_lo) @ W2 -> 4 mfma  (fp32-fidelity, err ~1e-6)
// Fragment layouts (m89/m156-verified): A row=lane&15, k-octet=lane>>4;
// B col=lane&15, k-octet=lane>>4; D col=lane&15, row=(lane>>4)*4+r.
// Replaces ~608 FMA + ~330 DS instr per 16 edges with 10 MFMA + 5 ds_read_b128
// + 40 ds_write_b16. Gather prefetched one tile ahead (regs), atomics issued
// after next tile's gathers -> never drained on the critical path.
// ---------------------------------------------------------------------------
struct IDX { int ss, sd, ra0, ra1, ra2, ra3; };

__launch_bounds__(256, 3)
__global__ void edge_kernel_mfma(const void* __restrict__ nraw,
                                 const void* __restrict__ eraw,
                                 const int*  __restrict__ ei) {
    if (g_flags[0] == 0) return;   // fp32 inputs -> VALU fallback kernel runs
    const int lane = threadIdx.x & 63;
    const int wv   = threadIdx.x >> 6;
    const int jc   = lane & 15;    // M-row / N-col / D-col lane index
    const int gq   = lane >> 4;    // k-octet group
    const bool i64 = (g_flags[1] != 0);

    const ushort_t* n16 = (const ushort_t*)nraw;
    const ushort_t* e16 = (const ushort_t*)eraw;

    // --- B fragments, pinned in VGPRs (32 regs total; old path used 88) ---
    union FR { int i[4]; bf16x8 v; };
    FR w1f[2][3];   // [n-tile][k-step]
    FR w2f[2];      // [n-tile]
#pragma unroll
    for (int t = 0; t < 2; t++)
#pragma unroll
        for (int kk = 0; kk < 3; kk++)
#pragma unroll
            for (int q = 0; q < 4; q++) {
                int k0 = 32 * kk + 8 * gq + 2 * q;
                int lo = g_Wbf1[(k0 + 0) * 32 + 16 * t + jc];
                int hi = g_Wbf1[(k0 + 1) * 32 + 16 * t + jc];
                w1f[t][kk].i[q] = (lo & 0xffff) | (hi << 16);
            }
#pragma unroll
    for (int t = 0; t < 2; t++)
#pragma unroll
        for (int q = 0; q < 4; q++) {
            int k0 = 8 * gq + 2 * q;
            int lo = g_Wbf2[(k0 + 0) * 32 + 16 * t + jc];
            int hi = g_Wbf2[(k0 + 1) * 32 + 16 * t + jc];
            w2f[t].i[q] = (lo & 0xffff) | (hi << 16);
        }
    // pin against rematerialization of the global loads inside the loop
#pragma unroll
    for (int t = 0; t < 2; t++) {
#pragma unroll
        for (int kk = 0; kk < 3; kk++)
#pragma unroll
            for (int q = 0; q < 4; q++) asm volatile("" : "+v"(w1f[t][kk].i[q]));
#pragma unroll
        for (int q = 0; q < 4; q++) asm volatile("" : "+v"(w2f[t].i[q]));
    }
    float b1c[2], b2c[2];
#pragma unroll
    for (int t = 0; t < 2; t++) {
        b1c[t] = g_W[EB1_O + 16 * t + jc];
        b2c[t] = g_W[EB2_O + 16 * t + jc];
    }

    // per-wave LDS tiles (no cross-wave sharing -> zero barriers in the loop)
    // X: [16 edges][104 bf16]  stride 208B = 16B-aligned rows, 2-way banks max
    // H: [2 planes][16 edges][40 bf16] stride 80B, same properties
    __shared__ __align__(16) ushort_t Xs[4][16 * 104];
    __shared__ __align__(16) ushort_t Hs[4][2][16 * 40];

    // XCD-private accumulator slice: atomics stay in this XCD's L2
    unsigned xcc;
    asm volatile("s_getreg_b32 %0, hwreg(HW_REG_XCC_ID)" : "=s"(xcc));
    float* nup = g_nup + (xcc & 7) * NUP_STRIDE;

    const int stride = gridDim.x * 4;
    int tile = blockIdx.x * 4 + wv;
    if (tile >= E_TILES) return;

    IDX cur, nxt;
    ushort_t xr[24];
    const int pb = 24 * gq;   // this lane's position window in the 96-wide row

    auto issue_idx = [&](int tt, IDX& o) {
        const int e0 = tt * 16;
        const int es = e0 + jc;          // self edge (gather)
        const int ea = e0 + 4 * gq;      // atomic edges base
        if (i64) {   // low dword only (values < 2^31): no truncation op
            o.ss  = ei[2 * es];  o.sd  = ei[2 * (N_EDGES + es)];
            o.ra0 = ei[2 * (ea + 0)]; o.ra1 = ei[2 * (ea + 1)];
            o.ra2 = ei[2 * (ea + 2)]; o.ra3 = ei[2 * (ea + 3)];
        } else {
            o.ss  = ei[es];      o.sd  = ei[N_EDGES + es];
            o.ra0 = ei[ea + 0];  o.ra1 = ei[ea + 1];
            o.ra2 = ei[ea + 2];  o.ra3 = ei[ea + 3];
        }
    };

    auto issue_gather = [&](int tt, const IDX& o) {
        int sv = o.ss; if ((unsigned)sv >= N_NODES) sv = 0;
        int dv = o.sd; if ((unsigned)dv >= N_NODES) dv = 0;
        const size_t eh = (size_t)tt * 16 + jc;
        uintptr_t Bsrc = (uintptr_t)(n16 + (size_t)sv * 39);
        uintptr_t Bef  = (uintptr_t)(e16 + eh * 10) - 78;   // -39 elems
        uintptr_t Bdst = (uintptr_t)(n16 + (size_t)dv * 39) - 98; // -49 elems
#pragma unroll
        for (int i = 0; i < 24; i++) {
            int p = pb + i;
            uintptr_t A = (p < 39) ? Bsrc
                        : (p < 49) ? Bef
                        : (p < 88) ? Bdst
                                   : (Bsrc - 2 * (uintptr_t)p);  // safe dummy
            xr[i] = *(const ushort_t*)(A + 2 * (uintptr_t)p);
        }
    };

    // prologue
    issue_idx(tile, cur);
    issue_gather(tile, cur);

    while (true) {
        const int  tn = tile + stride;
        const bool hn = (tn < E_TILES);
        if (hn) issue_idx(tn, nxt);

        // commit prefetched x -> LDS (bf16 raw; pad positions written as 0 so
        // stale LDS can never inject NaN through the zero weight rows)
#pragma unroll
        for (int i = 0; i < 24; i++) {
            int p = pb + i;
            Xs[wv][jc * 104 + p] = (p < 88) ? xr[i] : (ushort_t)0;
        }

        // layer 1: 6 MFMA over K=96, two N-tiles
        f32x4 acc[2];
#pragma unroll
        for (int t = 0; t < 2; t++) acc[t] = (f32x4){b1c[t], b1c[t], b1c[t], b1c[t]};
#pragma unroll
        for (int kk = 0; kk < 3; kk++) {
            bf16x8 a = *(const bf16x8*)&Xs[wv][jc * 104 + 32 * kk + 8 * gq];
            acc[0] = __builtin_amdgcn_mfma_f32_16x16x32_bf16(a, w1f[0][kk].v, acc[0], 0, 0, 0);
            acc[1] = __builtin_amdgcn_mfma_f32_16x16x32_bf16(a, w1f[1][kk].v, acc[1], 0, 0, 0);
        }

        // h = tanh(.), split into bf16 hi+lo planes (keeps fp32 fidelity)
#pragma unroll
        for (int t = 0; t < 2; t++)
#pragma unroll
            for (int r = 0; r < 4; r++) {
                float h  = fast_tanh(acc[t][r]);
                ushort_t hh = f2bf_rne(h);
                ushort_t hl = f2bf_rne(h - bf2f(hh));
                int idx = (4 * gq + r) * 40 + 16 * t + jc;
                Hs[wv][0][idx] = hh;
                Hs[wv][1][idx] = hl;
            }

        // prefetch next tile's gathers (HBM/L2 latency hides under layer 2)
        if (hn) issue_gather(tn, nxt);

        // layer 2: (h_hi + h_lo) @ W2, 4 MFMA
        f32x4 a2[2];
#pragma unroll
        for (int t = 0; t < 2; t++) a2[t] = (f32x4){b2c[t], b2c[t], b2c[t], b2c[t]};
#pragma unroll
        for (int pl = 0; pl < 2; pl++) {
            bf16x8 ah = *(const bf16x8*)&Hs[wv][pl][jc * 40 + 8 * gq];
            a2[0] = __builtin_amdgcn_mfma_f32_16x16x32_bf16(ah, w2f[0].v, a2[0], 0, 0, 0);
            a2[1] = __builtin_amdgcn_mfma_f32_16x16x32_bf16(ah, w2f[1].v, a2[1], 0, 0, 0);
        }

        // e_up = tanh -> XCD-local atomics (fire-and-forget, commit under next iter)
        int ra[4] = {cur.ra0, cur.ra1, cur.ra2, cur.ra3};
#pragma unroll
        for (int r = 0; r < 4; r++) {
            int sv = ra[r]; if ((unsigned)sv >= N_NODES) sv = 0;
#pragma unroll
            for (int t = 0; t < 2; t++)
                __hip_atomic_fetch_add(&nup[sv * 32 + 16 * t + jc], fast_tanh(a2[t][r]),
                                       __ATOMIC_RELAXED, __HIP_MEMORY_SCOPE_WORKGROUP);
        }

        if (!hn) break;
        tile = tn;
        cur = nxt;
    }
}

// ---------------------------------------------------------------------------
// VALU fallback (fp32 inputs): round-1 kernel, flag-gated.
// ---------------------------------------------------------------------------
__launch_bounds__(256, 2)
__global__ void edge_kernel_valu(const void* __restrict__ nraw,
                                 const void* __restrict__ eraw,
                                 const int*  __restrict__ ei) {
    if (g_flags[0] != 0) return;   // bf16 inputs -> MFMA kernel runs
    const int lane = threadIdx.x & 63;
    const int wv   = threadIdx.x >> 6;
    const int jcol = lane & 31;
    const int half = lane >> 5;
    const bool bf  = false;
    const bool i64 = (g_flags[1] != 0);

    float w1c[88];
#pragma unroll
    for (int r = 0; r < 88; r++) w1c[r] = g_W[EW1_O + r * 32 + jcol];
#pragma unroll
    for (int r = 0; r < 88; r++) asm volatile("" : "+v"(w1c[r]));
    const float b1 = g_W[EB1_O + jcol];
    const float b2 = g_W[EB2_O + jcol];

    __shared__ __align__(16) float sx[4][4][2][96];
    __shared__ __align__(16) float sh[4][4][2][32];
    __shared__ __align__(16) float s_w2[1024];
    for (int i = threadIdx.x; i < 1024; i += 256) s_w2[i] = g_W[EW2_O + i];
    __syncthreads();

    unsigned xcc;
    asm volatile("s_getreg_b32 %0, hwreg(HW_REG_XCC_ID)" : "=s"(xcc));
    float* nup = g_nup + (xcc & 7) * NUP_STRIDE;

    const unsigned short* n16 = (const unsigned short*)nraw;
    const unsigned short* e16 = (const unsigned short*)eraw;
    const float*          n32 = (const float*)nraw;
    const float*          e32 = (const float*)eraw;

    const int stride = gridDim.x * 4;
    int g = blockIdx.x * 4 + wv;
    if (g >= E_GROUPS) return;

    int   rs[4], rd[4];
    float xr[12];
    int   srcs[4], srcs_n[4];

    auto issue_idx = [&](int gg) {
        const int e0 = gg * 8 + half * 4;
#pragma unroll
        for (int s = 0; s < 4; s++) {
            const int eh = e0 + s;
            if (i64) { rs[s] = ei[2 * eh]; rd[s] = ei[2 * (N_EDGES + eh)]; }
            else     { rs[s] = ei[eh];     rd[s] = ei[N_EDGES + eh]; }
        }
    };

    auto issue_gather = [&](int gg, int* sv_out) {
        const int e0 = gg * 8 + half * 4;
#pragma unroll
        for (int s = 0; s < 4; s++) {
            int sv = rs[s]; if ((unsigned)sv >= N_NODES) sv = 0;
            int dv = rd[s]; if ((unsigned)dv >= N_NODES) dv = 0;
            sv_out[s] = sv;
            const int eh = e0 + s;
#pragma unroll
            for (int it = 0; it < 3; it++) {
                const int t = jcol + it * 32;
                float v = 0.0f;
                if (t < 88) {
                    if (t < 39)      v = bf ? bf2f(n16[sv * 39 + t]) : n32[sv * 39 + t];
                    else if (t < 49) v = bf ? bf2f(e16[(long long)eh * 10 + (t - 39)])
                                            : e32[(long long)eh * 10 + (t - 39)];
                    else             v = bf ? bf2f(n16[dv * 39 + (t - 49)])
                                            : n32[dv * 39 + (t - 49)];
                }
                xr[s * 3 + it] = v;
            }
        }
    };

    issue_idx(g);
    issue_gather(g, srcs);

    while (true) {
        const int  gn = g + stride;
        const bool hn = (gn < E_GROUPS);
        if (hn) issue_idx(gn);

#pragma unroll
        for (int s = 0; s < 4; s++)
#pragma unroll
            for (int it = 0; it < 3; it++) {
                const int t = jcol + it * 32;
                if (t < 88) sx[wv][s][half][t] = xr[s * 3 + it];
            }

        float acc0 = b1, acc1 = b1, acc2 = b1, acc3 = b1;
#pragma unroll
        for (int q = 0; q < 22; q++) {
            float4 x0 = ((const float4*)sx[wv][0][half])[q];
            float4 x1 = ((const float4*)sx[wv][1][half])[q];
            float4 x2 = ((const float4*)sx[wv][2][half])[q];
            float4 x3 = ((const float4*)sx[wv][3][half])[q];
            acc0 = fmaf(x0.x, w1c[4*q+0], acc0); acc0 = fmaf(x0.y, w1c[4*q+1], acc0);
            acc0 = fmaf(x0.z, w1c[4*q+2], acc0); acc0 = fmaf(x0.w, w1c[4*q+3], acc0);
            acc1 = fmaf(x1.x, w1c[4*q+0], acc1); acc1 = fmaf(x1.y, w1c[4*q+1], acc1);
            acc1 = fmaf(x1.z, w1c[4*q+2], acc1); acc1 = fmaf(x1.w, w1c[4*q+3], acc1);
            acc2 = fmaf(x2.x, w1c[4*q+0], acc2); acc2 = fmaf(x2.y, w1c[4*q+1], acc2);
            acc2 = fmaf(x2.z, w1c[4*q+2], acc2); acc2 = fmaf(x2.w, w1c[4*q+3], acc2);
            acc3 = fmaf(x3.x, w1c[4*q+0], acc3); acc3 = fmaf(x3.y, w1c[4*q+1], acc3);
            acc3 = fmaf(x3.z, w1c[4*q+2], acc3); acc3 = fmaf(x3.w, w1c[4*q+3], acc3);
        }
        sh[wv][0][half][jcol] = fast_tanh(acc0);
        sh[wv][1][half][jcol] = fast_tanh(acc1);
        sh[wv][2][half][jcol] = fast_tanh(acc2);
        sh[wv][3][half][jcol] = fast_tanh(acc3);

        if (hn) issue_gather(gn, srcs_n);

        float a0 = b2, a1 = b2, a2 = b2, a3 = b2;
#pragma unroll
        for (int q = 0; q < 8; q++) {
            float4 h0 = ((const float4*)sh[wv][0][half])[q];
            float4 h1 = ((const float4*)sh[wv][1][half])[q];
            float4 h2 = ((const float4*)sh[wv][2][half])[q];
            float4 h3 = ((const float4*)sh[wv][3][half])[q];
            const float wa = s_w2[(4*q+0)*32 + jcol];
            const float wb = s_w2[(4*q+1)*32 + jcol];
            const float wc = s_w2[(4*q+2)*32 + jcol];
            const float wd = s_w2[(4*q+3)*32 + jcol];
            a0 = fmaf(h0.x, wa, a0); a0 = fmaf(h0.y, wb, a0);
            a0 = fmaf(h0.z, wc, a0); a0 = fmaf(h0.w, wd, a0);
            a1 = fmaf(h1.x, wa, a1); a1 = fmaf(h1.y, wb, a1);
            a1 = fmaf(h1.z, wc, a1); a1 = fmaf(h1.w, wd, a1);
            a2 = fmaf(h2.x, wa, a2); a2 = fmaf(h2.y, wb, a2);
            a2 = fmaf(h2.z, wc, a2); a2 = fmaf(h2.w, wd, a2);
            a3 = fmaf(h3.x, wa, a3); a3 = fmaf(h3.y, wb, a3);
            a3 = fmaf(h3.z, wc, a3); a3 = fmaf(h3.w, wd, a3);
        }

        __hip_atomic_fetch_add(&nup[srcs[0] * 32 + jcol], fast_tanh(a0),
                               __ATOMIC_RELAXED, __HIP_MEMORY_SCOPE_WORKGROUP);
        __hip_atomic_fetch_add(&nup[srcs[1] * 32 + jcol], fast_tanh(a1),
                               __ATOMIC_RELAXED, __HIP_MEMORY_SCOPE_WORKGROUP);
        __hip_atomic_fetch_add(&nup[srcs[2] * 32 + jcol], fast_tanh(a2),
                               __ATOMIC_RELAXED, __HIP_MEMORY_SCOPE_WORKGROUP);
        __hip_atomic_fetch_add(&nup[srcs[3] * 32 + jcol], fast_tanh(a3),
                               __ATOMIC_RELAXED, __HIP_MEMORY_SCOPE_WORKGROUP);

        if (!hn) break;
        g = gn;
#pragma unroll
        for (int s = 0; s < 4; s++) srcs[s] = srcs_n[s];
    }
}

// Wave-cooperative node MLP, ILP-4: one wave = 8 nodes. Sums the 8 XCD-private
// n_up copies during the gather phase.
__launch_bounds__(256, 2)
__global__ void node_kernel(const void* __restrict__ nraw,
                            float* __restrict__ out) {
    const int lane = threadIdx.x & 63;
    const int wv   = threadIdx.x >> 6;
    const int jcol = lane & 31;
    const int half = lane >> 5;
    const bool bf  = (g_flags[0] != 0);

    float w1c[72];
#pragma unroll
    for (int r = 0; r < 71; r++) w1c[r] = g_W[NW1_O + r * 32 + jcol];
    w1c[71] = 0.0f;
#pragma unroll
    for (int r = 0; r < 72; r++) asm volatile("" : "+v"(w1c[r]));
    const float w2e = g_W[NW2_O + jcol];
    const float b1  = g_W[NB1_O + jcol];
    const float b2  = g_W[NB2_O];

    __shared__ __align__(16) float sx[4][4][2][72];

    const unsigned short* n16 = (const unsigned short*)nraw;
    const float*          n32 = (const float*)nraw;

    int gw = blockIdx.x * 4 + wv;
    int stride = gridDim.x * 4;
    for (int g = gw; g < N_GROUPS; g += stride) {
        const int id0 = g * 8 + half * 4;
#pragma unroll
        for (int s = 0; s < 4; s++) {
            const int id = id0 + s;
#pragma unroll
            for (int it = 0; it < 3; it++) {
                int t = jcol + it * 32;
                if (t < 72) {
                    float v;
                    if (t < 32) {
                        const float* p = g_nup + id * 32 + t;
                        v = p[0];
#pragma unroll
                        for (int x = 1; x < NXCD; x++) v += p[x * NUP_STRIDE];
                    }
                    else if (t < 71) v = bf ? bf2f(n16[id * 39 + (t - 32)])
                                            : n32[id * 39 + (t - 32)];
                    else             v = 0.0f;
                    sx[wv][s][half][t] = v;
                }
            }
        }
        float acc0 = b1, acc1 = b1, acc2 = b1, acc3 = b1;
#pragma unroll
        for (int q = 0; q < 18; q++) {
            float4 x0 = ((const float4*)sx[wv][0][half])[q];
            float4 x1 = ((const float4*)sx[wv][1][half])[q];
            float4 x2 = ((const float4*)sx[wv][2][half])[q];
            float4 x3 = ((const float4*)sx[wv][3][half])[q];
            acc0 = fmaf(x0.x, w1c[4*q+0], acc0); acc0 = fmaf(x0.y, w1c[4*q+1], acc0);
            acc0 = fmaf(x0.z, w1c[4*q+2], acc0); acc0 = fmaf(x0.w, w1c[4*q+3], acc0);
            acc1 = fmaf(x1.x, w1c[4*q+0], acc1); acc1 = fmaf(x1.y, w1c[4*q+1], acc1);
            acc1 = fmaf(x1.z, w1c[4*q+2], acc1); acc1 = fmaf(x1.w, w1c[4*q+3], acc1);
            acc2 = fmaf(x2.x, w1c[4*q+0], acc2); acc2 = fmaf(x2.y, w1c[4*q+1], acc2);
            acc2 = fmaf(x2.z, w1c[4*q+2], acc2); acc2 = fmaf(x2.w, w1c[4*q+3], acc2);
            acc3 = fmaf(x3.x, w1c[4*q+0], acc3); acc3 = fmaf(x3.y, w1c[4*q+1], acc3);
            acc3 = fmaf(x3.z, w1c[4*q+2], acc3); acc3 = fmaf(x3.w, w1c[4*q+3], acc3);
        }
        float t0 = fast_tanh(acc0) * w2e;
        float t1 = fast_tanh(acc1) * w2e;
        float t2 = fast_tanh(acc2) * w2e;
        float t3 = fast_tanh(acc3) * w2e;
#pragma unroll
        for (int m = 1; m < 32; m <<= 1) {
            t0 += __shfl_xor(t0, m, 64);
            t1 += __shfl_xor(t1, m, 64);
            t2 += __shfl_xor(t2, m, 64);
            t3 += __shfl_xor(t3, m, 64);
        }
        if (jcol == 0) {
            out[id0 + 0] = t0 + b2;
            out[id0 + 1] = t1 + b2;
            out[id0 + 2] = t2 + b2;
            out[id0 + 3] = t3 + b2;
        }
    }
}

extern "C" void kernel_launch(void* const* d_in, const int* in_sizes, int n_in,
                              void* d_out, int out_size, void* d_ws, size_t ws_size,
                              hipStream_t stream) {
    const void* n_raw = d_in[0];
    const void* e_raw = d_in[1];
    const int*  ei    = (const int*)d_in[2];
    // d_in[3] = batch (unused)

    detect_kernel<<<1, 256, 0, stream>>>((const unsigned short*)d_in[4], ei);
    zero_nup_kernel<<<(NXCD * NUP_STRIDE / 4 + 255) / 256, 256, 0, stream>>>();
    cvt_weights_kernel<<<16, 256, 0, stream>>>(d_in[4], d_in[5], d_in[6], d_in[7],
                                               d_in[8], d_in[9], d_in[10], d_in[11]);
    edge_kernel_mfma<<<2048, 256, 0, stream>>>(n_raw, e_raw, ei);
    edge_kernel_valu<<<1024, 256, 0, stream>>>(n_raw, e_raw, ei);
    node_kernel<<<512, 256, 0, stream>>>(n_raw, (float*)d_out);
}

// Round 4
// 917.010 us; speedup vs baseline: 1.8043x; 1.1529x over previous
//
#include <hip/hip_runtime.h>
#include <hip/hip_bf16.h>

#define N_NODES 100000
#define N_EDGES 3200000
#define E_TILES  (N_EDGES / 16)  // MFMA path: 16 edges per wave-iteration
#define N_GROUPS (N_NODES / 8)   // 8 nodes per wave-iteration
#define NXCD 8
#define NUP_STRIDE (N_NODES * 32)   // floats per XCD-private accumulator copy

// weight sub-offsets in g_W (fp32 copies)
#define EW1_O 0        // 88*32
#define EB1_O 2816     // 32
#define EW2_O 2848     // 32*32
#define EB2_O 3872     // 32
#define NW1_O 3904     // 71*32
#define NB1_O 6176     // 32
#define NW2_O 6208     // 32
#define NB2_O 6240     // 1

typedef unsigned short ushort_t;
typedef __attribute__((ext_vector_type(8))) short bf16x8;
typedef __attribute__((ext_vector_type(4))) float f32x4;

// Device-global state, rebuilt from inputs on EVERY call.
__device__ float    g_nup[NXCD * NUP_STRIDE];  // 8 XCD-private scatter copies
__device__ float    g_W[6244];                 // fp32 weights
__device__ ushort_t g_Wbf1[2][96 * 32];        // W1 split planes (hi,lo), K 88->96 pad
__device__ ushort_t g_Wbf2[2][32 * 32];        // W2 split planes (hi,lo)
__device__ int      g_flags[2];                // [0]: 1=bf16 floats; [1]: 1=int64 idx

__device__ __forceinline__ float bf2f(unsigned short u) {
    union { unsigned int i; float f; } c;
    c.i = ((unsigned int)u) << 16;
    return c.f;
}
__device__ __forceinline__ float ubf2f(unsigned u) {
    union { unsigned int i; float f; } c;
    c.i = u << 16;
    return c.f;
}
// round-to-nearest-even fp32 -> bf16 (low 16 bits of result valid)
__device__ __forceinline__ unsigned f2bf_u(float f) {
    union { float f; unsigned u; } c;
    c.f = f;
    return (c.u + 0x7fffu + ((c.u >> 16) & 1u)) >> 16;
}

__device__ __forceinline__ float rd_any(const void* p, int i, bool bf) {
    if (bf) return bf2f(((const unsigned short*)p)[i]);
    return ((const float*)p)[i];
}

// tanh via hardware exp2: ~6 VALU inst. |err| ~1e-6 (validated: absmax 9.8e-4).
__device__ __forceinline__ float fast_tanh(float x) {
    float ax = fabsf(x);
    float e  = __expf(ax * 2.0f);
    float t  = 1.0f - 2.0f / (e + 1.0f);
    return copysignf(t, x);
}

__global__ void detect_kernel(const unsigned short* __restrict__ ew1_raw,
                              const int* __restrict__ ei32) {
    __shared__ int s_ok, s_nzodd;
    if (threadIdx.x == 0) { s_ok = 1; s_nzodd = 0; }
    __syncthreads();
    bool ok = true;
    for (int i = threadIdx.x; i < 2816; i += 256) {
        float v = bf2f(ew1_raw[i]);
        if (!(fabsf(v) <= 0.25f)) ok = false;
    }
    if (!ok) atomicAnd(&s_ok, 0);
    int cnt = 0;
    for (int i = threadIdx.x; i < 2048; i += 256)
        if (ei32[2 * i + 1] != 0) cnt++;
    if (cnt) atomicAdd(&s_nzodd, cnt);
    __syncthreads();
    if (threadIdx.x == 0) {
        g_flags[0] = s_ok;
        g_flags[1] = (s_nzodd < 16) ? 1 : 0;
    }
}

__global__ void zero_nup_kernel() {
    int i = blockIdx.x * 256 + threadIdx.x;
    if (i < NXCD * NUP_STRIDE / 4) ((float4*)g_nup)[i] = make_float4(0.f, 0.f, 0.f, 0.f);
}

__global__ void cvt_weights_kernel(const void* ew1, const void* eb1,
                                   const void* ew2, const void* eb2,
                                   const void* nw1, const void* nb1,
                                   const void* nw2, const void* nb2) {
    bool bf = (g_flags[0] != 0);
    int t = blockIdx.x * blockDim.x + threadIdx.x;
    int S = gridDim.x * blockDim.x;
    for (int i = t; i < 2816; i += S) g_W[EW1_O + i] = rd_any(ew1, i, bf);
    for (int i = t; i < 32;   i += S) g_W[EB1_O + i] = rd_any(eb1, i, bf);
    for (int i = t; i < 1024; i += S) g_W[EW2_O + i] = rd_any(ew2, i, bf);
    for (int i = t; i < 32;   i += S) g_W[EB2_O + i] = rd_any(eb2, i, bf);
    for (int i = t; i < 2272; i += S) g_W[NW1_O + i] = rd_any(nw1, i, bf);
    for (int i = t; i < 32;   i += S) g_W[NB1_O + i] = rd_any(nb1, i, bf);
    for (int i = t; i < 32;   i += S) g_W[NW2_O + i] = rd_any(nw2, i, bf);
    if (t == 0) g_W[NB2_O] = rd_any(nb2, 0, bf);
    // split-bf16 planes: w = hi + lo with |w - hi - lo| <= 2^-17 |w|.
    // pad rows (r>=88) are zero so LDS pad garbage can never inject NaN.
    for (int i = t; i < 96 * 32; i += S) {
        int r = i >> 5;
        float w = (r < 88) ? rd_any(ew1, i, bf) : 0.0f;
        unsigned h = f2bf_u(w);
        unsigned l = f2bf_u(w - ubf2f(h));
        g_Wbf1[0][i] = (ushort_t)h;
        g_Wbf1[1][i] = (ushort_t)l;
    }
    for (int i = t; i < 1024; i += S) {
        float w = rd_any(ew2, i, bf);
        unsigned h = f2bf_u(w);
        unsigned l = f2bf_u(w - ubf2f(h));
        g_Wbf2[0][i] = (ushort_t)h;
        g_Wbf2[1][i] = (ushort_t)l;
    }
}

// ---------------------------------------------------------------------------
// MFMA edge kernel, fp32-or-bf16 inputs via split-bf16 planes.
// One wave = 16 edges/iter.
//   layer1: X[16x96] @ W1[96x32]:  Xhi@Whi + Xhi@Wlo + Xlo@Whi  -> 18 mfma
//   layer2: H[16x32] @ W2[32x32]:  Hhi@W2hi + Hhi@W2lo + Hlo@W2hi -> 6 mfma
// Dropped lo*lo terms ~2^-16 relative: added error ~1e-5 (<< fast_tanh's 1e-3).
// Fragment layouts (m89-verified): A row=lane&15, k=8*(lane>>4)+j;
// B col=lane&15, same k map; D col=lane&15, row=4*(lane>>4)+r.
// Gather: 4-way gq-divergent compile-time windows -> zero per-element address
// selection VALU; loads carry immediate offsets. Pipeline: idx+gather prefetch
// one tile ahead; atomics issued after next tile's gathers (never drained on
// the critical path). Atomics: XCD-private copy, workgroup scope (L2-local).
// ---------------------------------------------------------------------------
struct IDX { int ss, sd, ra0, ra1, ra2, ra3; };

template<int PB, bool BF>
__device__ __forceinline__ void loadwin(float* xr, const void* ns,
                                        const void* ef, const void* nd) {
#pragma unroll
    for (int i = 0; i < 24; i++) {
        const int p = PB + i;   // compile-time: branch below folds away
        float v;
        if (p < 39)      v = BF ? bf2f(((const ushort_t*)ns)[p])      : ((const float*)ns)[p];
        else if (p < 49) v = BF ? bf2f(((const ushort_t*)ef)[p - 39]) : ((const float*)ef)[p - 39];
        else if (p < 88) v = BF ? bf2f(((const ushort_t*)nd)[p - 49]) : ((const float*)nd)[p - 49];
        else             v = 0.0f;
        xr[i] = v;
    }
}

__launch_bounds__(256, 3)
__global__ void edge_kernel_mfma(const void* __restrict__ nraw,
                                 const void* __restrict__ eraw,
                                 const int*  __restrict__ ei) {
    const int lane = threadIdx.x & 63;
    const int wv   = threadIdx.x >> 6;
    const int jc   = lane & 15;    // edge-in-tile (gather) / D-col / A-row
    const int gq   = lane >> 4;    // k-octet group
    const bool bf  = (g_flags[0] != 0);
    const bool i64 = (g_flags[1] != 0);

    const ushort_t* n16 = (const ushort_t*)nraw;
    const ushort_t* e16 = (const ushort_t*)eraw;
    const float*    n32 = (const float*)nraw;
    const float*    e32 = (const float*)eraw;

    // --- B fragments, pinned in VGPRs: 48 (W1 hi+lo) + 16 (W2 hi+lo) ---
    union FR { int i[4]; bf16x8 v; };
    FR w1f[2][2][3];   // [plane][n-tile][k-step]
    FR w2f[2][2];      // [plane][n-tile]
#pragma unroll
    for (int pl = 0; pl < 2; pl++)
#pragma unroll
        for (int t = 0; t < 2; t++)
#pragma unroll
            for (int kk = 0; kk < 3; kk++)
#pragma unroll
                for (int q = 0; q < 4; q++) {
                    int k0 = 32 * kk + 8 * gq + 2 * q;
                    int lo = g_Wbf1[pl][(k0 + 0) * 32 + 16 * t + jc];
                    int hi = g_Wbf1[pl][(k0 + 1) * 32 + 16 * t + jc];
                    w1f[pl][t][kk].i[q] = (lo & 0xffff) | (hi << 16);
                }
#pragma unroll
    for (int pl = 0; pl < 2; pl++)
#pragma unroll
        for (int t = 0; t < 2; t++)
#pragma unroll
            for (int q = 0; q < 4; q++) {
                int k0 = 8 * gq + 2 * q;
                int lo = g_Wbf2[pl][(k0 + 0) * 32 + 16 * t + jc];
                int hi = g_Wbf2[pl][(k0 + 1) * 32 + 16 * t + jc];
                w2f[pl][t].i[q] = (lo & 0xffff) | (hi << 16);
            }
#pragma unroll
    for (int pl = 0; pl < 2; pl++) {
#pragma unroll
        for (int t = 0; t < 2; t++) {
#pragma unroll
            for (int kk = 0; kk < 3; kk++)
#pragma unroll
                for (int q = 0; q < 4; q++) asm volatile("" : "+v"(w1f[pl][t][kk].i[q]));
#pragma unroll
            for (int q = 0; q < 4; q++) asm volatile("" : "+v"(w2f[pl][t].i[q]));
        }
    }
    float b1c[2], b2c[2];
#pragma unroll
    for (int t = 0; t < 2; t++) {
        b1c[t] = g_W[EB1_O + 16 * t + jc];
        b2c[t] = g_W[EB2_O + 16 * t + jc];
    }

    // per-wave LDS (no cross-wave sharing -> zero barriers):
    // X planes: [16 edges][104], row stride 208B (16B mult, 2-way banks on b128)
    // H planes: [16 edges][40],  row stride 80B  (16B mult, 2-way banks)
    __shared__ __align__(16) ushort_t XsH[4][16 * 104];
    __shared__ __align__(16) ushort_t XsL[4][16 * 104];
    __shared__ __align__(16) ushort_t HsH[4][16 * 40];
    __shared__ __align__(16) ushort_t HsL[4][16 * 40];

    unsigned xcc;
    asm volatile("s_getreg_b32 %0, hwreg(HW_REG_XCC_ID)" : "=s"(xcc));
    float* nup = g_nup + (xcc & 7) * NUP_STRIDE;

    const int stride = gridDim.x * 4;
    int tile = blockIdx.x * 4 + wv;
    if (tile >= E_TILES) return;

    IDX cur, nxt;
    float xr[24];

    auto issue_idx = [&](int tt, IDX& o) {
        const int e0 = tt * 16;
        const int es = e0 + jc;          // this lane's gather edge
        const int ea = e0 + 4 * gq;      // this lane's atomic edges base
        if (i64) {   // low dword only (ids < 2^31): no truncation op
            o.ss  = ei[2 * es];       o.sd  = ei[2 * (N_EDGES + es)];
            o.ra0 = ei[2 * (ea + 0)]; o.ra1 = ei[2 * (ea + 1)];
            o.ra2 = ei[2 * (ea + 2)]; o.ra3 = ei[2 * (ea + 3)];
        } else {
            o.ss  = ei[es];      o.sd  = ei[N_EDGES + es];
            o.ra0 = ei[ea + 0];  o.ra1 = ei[ea + 1];
            o.ra2 = ei[ea + 2];  o.ra3 = ei[ea + 3];
        }
    };

    auto issue_gather = [&](int tt, const IDX& o) {
        int sv = o.ss; if ((unsigned)sv >= N_NODES) sv = 0;
        int dv = o.sd; if ((unsigned)dv >= N_NODES) dv = 0;
        const size_t eh = (size_t)tt * 16 + jc;
        if (bf) {
            const void* ns = (const void*)(n16 + (size_t)sv * 39);
            const void* ef = (const void*)(e16 + eh * 10);
            const void* nd = (const void*)(n16 + (size_t)dv * 39);
            if      (gq == 0) loadwin<0,  true>(xr, ns, ef, nd);
            else if (gq == 1) loadwin<24, true>(xr, ns, ef, nd);
            else if (gq == 2) loadwin<48, true>(xr, ns, ef, nd);
            else              loadwin<72, true>(xr, ns, ef, nd);
        } else {
            const void* ns = (const void*)(n32 + (size_t)sv * 39);
            const void* ef = (const void*)(e32 + eh * 10);
            const void* nd = (const void*)(n32 + (size_t)dv * 39);
            if      (gq == 0) loadwin<0,  false>(xr, ns, ef, nd);
            else if (gq == 1) loadwin<24, false>(xr, ns, ef, nd);
            else if (gq == 2) loadwin<48, false>(xr, ns, ef, nd);
            else              loadwin<72, false>(xr, ns, ef, nd);
        }
    };

    // prologue
    issue_idx(tile, cur);
    issue_gather(tile, cur);

    while (true) {
        const int  tn = tile + stride;
        const bool hn = (tn < E_TILES);
        if (hn) issue_idx(tn, nxt);

        // commit prefetched x -> split-bf16 LDS planes (12 packed b32 writes each)
        {
            unsigned* xh32 = (unsigned*)&XsH[wv][0];
            unsigned* xl32 = (unsigned*)&XsL[wv][0];
            const int wb = jc * 52 + gq * 12;
#pragma unroll
            for (int w = 0; w < 12; w++) {
                float a = xr[2 * w], b = xr[2 * w + 1];
                unsigned ha = f2bf_u(a), hb = f2bf_u(b);
                unsigned la = f2bf_u(a - ubf2f(ha));
                unsigned lb = f2bf_u(b - ubf2f(hb));
                xh32[wb + w] = (ha & 0xffffu) | (hb << 16);
                xl32[wb + w] = (la & 0xffffu) | (lb << 16);
            }
        }

        // layer 1: 18 MFMA (3 split terms x 3 k-steps x 2 n-tiles)
        f32x4 acc[2];
#pragma unroll
        for (int t = 0; t < 2; t++) acc[t] = (f32x4){b1c[t], b1c[t], b1c[t], b1c[t]};
#pragma unroll
        for (int kk = 0; kk < 3; kk++) {
            bf16x8 ah = *(const bf16x8*)&XsH[wv][jc * 104 + 32 * kk + 8 * gq];
            bf16x8 al = *(const bf16x8*)&XsL[wv][jc * 104 + 32 * kk + 8 * gq];
#pragma unroll
            for (int t = 0; t < 2; t++) {
                acc[t] = __builtin_amdgcn_mfma_f32_16x16x32_bf16(ah, w1f[0][t][kk].v, acc[t], 0, 0, 0);
                acc[t] = __builtin_amdgcn_mfma_f32_16x16x32_bf16(ah, w1f[1][t][kk].v, acc[t], 0, 0, 0);
                acc[t] = __builtin_amdgcn_mfma_f32_16x16x32_bf16(al, w1f[0][t][kk].v, acc[t], 0, 0, 0);
            }
        }

        // h = tanh(acc), split into hi+lo bf16 planes
#pragma unroll
        for (int t = 0; t < 2; t++)
#pragma unroll
            for (int r = 0; r < 4; r++) {
                float h = fast_tanh(acc[t][r]);
                unsigned hh = f2bf_u(h);
                unsigned hl = f2bf_u(h - ubf2f(hh));
                int idx = (4 * gq + r) * 40 + 16 * t + jc;
                HsH[wv][idx] = (ushort_t)hh;
                HsL[wv][idx] = (ushort_t)hl;
            }

        // prefetch next tile's gathers (HBM/L2 latency hides under layer 2)
        if (hn) issue_gather(tn, nxt);

        // layer 2: 6 MFMA
        f32x4 a2[2];
#pragma unroll
        for (int t = 0; t < 2; t++) a2[t] = (f32x4){b2c[t], b2c[t], b2c[t], b2c[t]};
        {
            bf16x8 hh8 = *(const bf16x8*)&HsH[wv][jc * 40 + 8 * gq];
            bf16x8 hl8 = *(const bf16x8*)&HsL[wv][jc * 40 + 8 * gq];
#pragma unroll
            for (int t = 0; t < 2; t++) {
                a2[t] = __builtin_amdgcn_mfma_f32_16x16x32_bf16(hh8, w2f[0][t].v, a2[t], 0, 0, 0);
                a2[t] = __builtin_amdgcn_mfma_f32_16x16x32_bf16(hh8, w2f[1][t].v, a2[t], 0, 0, 0);
                a2[t] = __builtin_amdgcn_mfma_f32_16x16x32_bf16(hl8, w2f[0][t].v, a2[t], 0, 0, 0);
            }
        }

        // e_up = tanh -> XCD-local atomics (fire-and-forget under next iter)
        int ra[4] = {cur.ra0, cur.ra1, cur.ra2, cur.ra3};
#pragma unroll
        for (int r = 0; r < 4; r++) {
            int sv = ra[r]; if ((unsigned)sv >= N_NODES) sv = 0;
#pragma unroll
            for (int t = 0; t < 2; t++)
                __hip_atomic_fetch_add(&nup[sv * 32 + 16 * t + jc], fast_tanh(a2[t][r]),
                                       __ATOMIC_RELAXED, __HIP_MEMORY_SCOPE_WORKGROUP);
        }

        if (!hn) break;
        tile = tn;
        cur = nxt;
    }
}

// Wave-cooperative node MLP, ILP-4: one wave = 8 nodes. Sums the 8 XCD-private
// n_up copies during the gather phase.
__launch_bounds__(256, 2)
__global__ void node_kernel(const void* __restrict__ nraw,
                            float* __restrict__ out) {
    const int lane = threadIdx.x & 63;
    const int wv   = threadIdx.x >> 6;
    const int jcol = lane & 31;
    const int half = lane >> 5;
    const bool bf  = (g_flags[0] != 0);

    float w1c[72];
#pragma unroll
    for (int r = 0; r < 71; r++) w1c[r] = g_W[NW1_O + r * 32 + jcol];
    w1c[71] = 0.0f;
#pragma unroll
    for (int r = 0; r < 72; r++) asm volatile("" : "+v"(w1c[r]));
    const float w2e = g_W[NW2_O + jcol];
    const float b1  = g_W[NB1_O + jcol];
    const float b2  = g_W[NB2_O];

    __shared__ __align__(16) float sx[4][4][2][72];

    const unsigned short* n16 = (const unsigned short*)nraw;
    const float*          n32 = (const float*)nraw;

    int gw = blockIdx.x * 4 + wv;
    int stride = gridDim.x * 4;
    for (int g = gw; g < N_GROUPS; g += stride) {
        const int id0 = g * 8 + half * 4;
#pragma unroll
        for (int s = 0; s < 4; s++) {
            const int id = id0 + s;
#pragma unroll
            for (int it = 0; it < 3; it++) {
                int t = jcol + it * 32;
                if (t < 72) {
                    float v;
                    if (t < 32) {
                        const float* p = g_nup + id * 32 + t;
                        v = p[0];
#pragma unroll
                        for (int x = 1; x < NXCD; x++) v += p[x * NUP_STRIDE];
                    }
                    else if (t < 71) v = bf ? bf2f(n16[id * 39 + (t - 32)])
                                            : n32[id * 39 + (t - 32)];
                    else             v = 0.0f;
                    sx[wv][s][half][t] = v;
                }
            }
        }
        float acc0 = b1, acc1 = b1, acc2 = b1, acc3 = b1;
#pragma unroll
        for (int q = 0; q < 18; q++) {
            float4 x0 = ((const float4*)sx[wv][0][half])[q];
            float4 x1 = ((const float4*)sx[wv][1][half])[q];
            float4 x2 = ((const float4*)sx[wv][2][half])[q];
            float4 x3 = ((const float4*)sx[wv][3][half])[q];
            acc0 = fmaf(x0.x, w1c[4*q+0], acc0); acc0 = fmaf(x0.y, w1c[4*q+1], acc0);
            acc0 = fmaf(x0.z, w1c[4*q+2], acc0); acc0 = fmaf(x0.w, w1c[4*q+3], acc0);
            acc1 = fmaf(x1.x, w1c[4*q+0], acc1); acc1 = fmaf(x1.y, w1c[4*q+1], acc1);
            acc1 = fmaf(x1.z, w1c[4*q+2], acc1); acc1 = fmaf(x1.w, w1c[4*q+3], acc1);
            acc2 = fmaf(x2.x, w1c[4*q+0], acc2); acc2 = fmaf(x2.y, w1c[4*q+1], acc2);
            acc2 = fmaf(x2.z, w1c[4*q+2], acc2); acc2 = fmaf(x2.w, w1c[4*q+3], acc2);
            acc3 = fmaf(x3.x, w1c[4*q+0], acc3); acc3 = fmaf(x3.y, w1c[4*q+1], acc3);
            acc3 = fmaf(x3.z, w1c[4*q+2], acc3); acc3 = fmaf(x3.w, w1c[4*q+3], acc3);
        }
        float t0 = fast_tanh(acc0) * w2e;
        float t1 = fast_tanh(acc1) * w2e;
        float t2 = fast_tanh(acc2) * w2e;
        float t3 = fast_tanh(acc3) * w2e;
#pragma unroll
        for (int m = 1; m < 32; m <<= 1) {
            t0 += __shfl_xor(t0, m, 64);
            t1 += __shfl_xor(t1, m, 64);
            t2 += __shfl_xor(t2, m, 64);
            t3 += __shfl_xor(t3, m, 64);
        }
        if (jcol == 0) {
            out[id0 + 0] = t0 + b2;
            out[id0 + 1] = t1 + b2;
            out[id0 + 2] = t2 + b2;
            out[id0 + 3] = t3 + b2;
        }
    }
}

extern "C" void kernel_launch(void* const* d_in, const int* in_sizes, int n_in,
                              void* d_out, int out_size, void* d_ws, size_t ws_size,
                              hipStream_t stream) {
    const void* n_raw = d_in[0];
    const void* e_raw = d_in[1];
    const int*  ei    = (const int*)d_in[2];
    // d_in[3] = batch (unused)

    detect_kernel<<<1, 256, 0, stream>>>((const unsigned short*)d_in[4], ei);
    zero_nup_kernel<<<(NXCD * NUP_STRIDE / 4 + 255) / 256, 256, 0, stream>>>();
    cvt_weights_kernel<<<16, 256, 0, stream>>>(d_in[4], d_in[5], d_in[6], d_in[7],
                                               d_in[8], d_in[9], d_in[10], d_in[11]);
    edge_kernel_mfma<<<2048, 256, 0, stream>>>(n_raw, e_raw, ei);
    node_kernel<<<512, 256, 0, stream>>>(n_raw, (float*)d_out);
}